// Round 10
// baseline (661.433 us; speedup 1.0000x reference)
//
#include <hip/hip_runtime.h>
#include <cstddef>
#include <cstdint>

#define B_ 2
#define D_ 12
#define H_ 200
#define W_ 200
#define HW_ (H_ * W_)
#define CELLS_ (B_ * D_ * H_ * W_)   // 960000
#define N_ 60000
#define CIN_ 2
#define COUT_ 64
#define K27 27
#define EPS_ 1e-5f
#define ZCHUNK 6                      // z-planes per block (12 % 6 == 0)

// padded dense feature map: [B][D+2][H+2][W+2] of packed fp16x2 (4 B/cell)
#define PD (D_ + 2)
#define PH (H_ + 2)
#define PW (W_ + 2)
#define PLANE (PH * PW)               // 40804
#define PF_INTS (B_ * PD * PLANE)     // 1,142,512 ints = 4.57 MB

typedef float  f32x4 __attribute__((ext_vector_type(4)));
typedef __fp16 h16x8 __attribute__((ext_vector_type(8)));
typedef __fp16 h16x2 __attribute__((ext_vector_type(2)));

union h2u   { h16x2 h; int u; };
union fragu { h16x8 v; int i[4]; };

__device__ __forceinline__ int pack_h2(float a, float b) {
    h2u t; t.h = __builtin_amdgcn_cvt_pkrtz(a, b); return t.u;
}

// ---------------------------------------------------------------------------
// Kernel A: build dense zero-padded fp16 feature map from scatter[13].
// ---------------------------------------------------------------------------
__global__ void build_featmap_kernel(const int* __restrict__ scatter,
                                     const float* __restrict__ feat,
                                     int* __restrict__ pf) {
    int n = blockIdx.x * blockDim.x + threadIdx.x;
    if (n >= N_) return;
    int lin = scatter[13 * N_ + n];
    int b = lin / (D_ * HW_);
    int r = lin % (D_ * HW_);
    int z = r / HW_;  r %= HW_;
    int y = r / W_;
    int x = r % W_;
    float2 f = *reinterpret_cast<const float2*>(feat + n * CIN_);
    pf[((b * PD + z + 1) * PH + y + 1) * PW + (x + 1)] = pack_h2(f.x, f.y);
}

// ---------------------------------------------------------------------------
// DPP 16-lane allreduce-add (VALU pipe, no LDS).
// ---------------------------------------------------------------------------
template <int CTRL>
__device__ __forceinline__ float dpp_add(float v) {
    int t = __builtin_amdgcn_update_dpp(
        0, __float_as_int(v), CTRL, 0xF, 0xF, true);
    return v + __int_as_float(t);
}
__device__ __forceinline__ float row16_allreduce_add(float v) {
    v = dpp_add<0x140>(v);  // row_mirror
    v = dpp_add<0x141>(v);  // row_half_mirror
    v = dpp_add<0x4E>(v);   // quad_perm i^2
    v = dpp_add<0xB1>(v);   // quad_perm i^1
    return v;
}

// ---------------------------------------------------------------------------
// Kernel B, round-10 = round-9 MFMA kernel, MEASUREMENT build: z-loop wrapped
// in reps (idempotent; asm clobber kills cross-rep CSE). reps=6 makes this
// dispatch top-1 in rocprof so we finally see its counters; per-rep cost =
// (dur_us - 278.1)/5.
// ---------------------------------------------------------------------------
__global__ __launch_bounds__(256) void conv_mfma_kernel(
        const int* __restrict__ pf,
        const float* __restrict__ weight,
        const float* __restrict__ gamma,
        const float* __restrict__ beta,
        float* __restrict__ out,
        int reps) {
    const int tid  = threadIdx.x;
    const int lane = tid & 63;
    const int wid  = tid >> 6;          // wave in block, 0..3
    const int col  = lane & 15;         // cell-in-strip (A row) / channel-low
    const int grp  = lane >> 4;         // k-slice group, 0..3

    const int ps = blockIdx.x * 4 + wid;        // plane strip id, 0..2499
    const int f  = ps * 16 + col;               // in-plane flat cell
    const int y  = f / W_;
    const int x  = f % W_;

    const int bz0 = blockIdx.y * ZCHUNK;        // first bz of chunk
    const int b   = (bz0 >= D_) ? 1 : 0;        // chunk never straddles b
    const int z0  = bz0 - b * D_;

    // ---- per-lane A voffsets: 2 K-steps x 4 taps (z-invariant) ----
    int voff[2][4];
    #pragma unroll
    for (int s = 0; s < 2; ++s) {
        #pragma unroll
        for (int i = 0; i < 4; ++i) {
            int t = grp * 4 + 16 * s + i;
            if (t <= 26) {
                int dz = t / 9, rr = t % 9, dy = rr / 3, dx = rr % 3;
                voff[s][i] = dz * PLANE + (y + dy) * PW + (x + dx);
            } else {
                voff[s][i] = 0;         // pad slot: reads padding zero
            }
        }
    }

    // ---- B fragments: same slot enumeration as A ----
    fragu bfr[2][4];
    #pragma unroll
    for (int s = 0; s < 2; ++s) {
        #pragma unroll
        for (int nt = 0; nt < 4; ++nt) {
            #pragma unroll
            for (int j2 = 0; j2 < 4; ++j2) {
                int t = grp * 4 + 16 * s + j2;
                float w0 = 0.f, w1 = 0.f;
                if (t <= 26) {
                    w0 = weight[t * (CIN_ * COUT_) + nt * 16 + col];
                    w1 = weight[t * (CIN_ * COUT_) + COUT_ + nt * 16 + col];
                }
                bfr[s][nt].i[j2] = pack_h2(w0, w1);
            }
        }
    }

    float gmv[4], btv[4];
    #pragma unroll
    for (int nt = 0; nt < 4; ++nt) {
        gmv[nt] = gamma[nt * 16 + col];
        btv[nt] = beta[nt * 16 + col];
    }

    const int obl = (ps * 16 + grp * 4) * COUT_ + col;

    for (int rep = 0; rep < reps; ++rep) {
        asm volatile("" ::: "memory");   // no cross-rep CSE/hoist

        for (int j = 0; j < ZCHUNK; ++j) {
            const int z  = z0 + j;
            const int bz = bz0 + j;
            const int zb = (b * PD + z) * PLANE;

            fragu af0, af1;
            #pragma unroll
            for (int i = 0; i < 4; ++i) af0.i[i] = pf[zb + voff[0][i]];
            #pragma unroll
            for (int i = 0; i < 4; ++i) af1.i[i] = pf[zb + voff[1][i]];

            int nz = 0;
            #pragma unroll
            for (int i = 0; i < 4; ++i) nz |= af0.i[i] & 0x7FFF7FFF;
            #pragma unroll
            for (int i = 0; i < 4; ++i) nz |= af1.i[i] & 0x7FFF7FFF;
            unsigned long long bal = __ballot(nz != 0);
            unsigned wfold = (unsigned)bal | (unsigned)(bal >> 16)
                           | (unsigned)(bal >> 32) | (unsigned)(bal >> 48);
            unsigned act4 = (wfold >> (grp * 4)) & 0xF;

            f32x4 acc[4];
            #pragma unroll
            for (int nt = 0; nt < 4; ++nt) {
                acc[nt] = (f32x4){0.f, 0.f, 0.f, 0.f};
                acc[nt] = __builtin_amdgcn_mfma_f32_16x16x32_f16(
                              af0.v, bfr[0][nt].v, acc[nt], 0, 0, 0);
                acc[nt] = __builtin_amdgcn_mfma_f32_16x16x32_f16(
                              af1.v, bfr[1][nt].v, acc[nt], 0, 0, 0);
            }

            float* op = out + (size_t)bz * (HW_ * COUT_) + obl;
            #pragma unroll
            for (int jj = 0; jj < 4; ++jj) {
                float a0 = acc[0][jj], a1 = acc[1][jj],
                      a2 = acc[2][jj], a3 = acc[3][jj];
                float s  = a0 + a1 + a2 + a3;
                float s2 = a0 * a0 + a1 * a1 + a2 * a2 + a3 * a3;
                s  = row16_allreduce_add(s);
                s2 = row16_allreduce_add(s2);
                float mu  = s * (1.0f / COUT_);
                float var = s2 * (1.0f / COUT_) - mu * mu;
                float inv = rsqrtf(var + EPS_);
                bool actj = (act4 >> jj) & 1;
                #pragma unroll
                for (int nt = 0; nt < 4; ++nt) {
                    float v  = acc[nt][jj];
                    float rv = fmaxf((v - mu) * inv * gmv[nt] + btv[nt],
                                     0.0f);
                    rv = actj ? rv : 0.0f;
                    __builtin_nontemporal_store(rv, op + jj * COUT_ + nt * 16);
                }
            }
        }
    }
}

extern "C" void kernel_launch(void* const* d_in, const int* in_sizes, int n_in,
                              void* d_out, int out_size, void* d_ws, size_t ws_size,
                              hipStream_t stream) {
    const float* feat    = (const float*)d_in[0];   // (N, 2)
    const float* weight  = (const float*)d_in[1];   // (27, 2, 64)
    const float* gamma   = (const float*)d_in[2];   // (64,)
    const float* beta    = (const float*)d_in[3];   // (64,)
    const int*   scatter = (const int*)d_in[4];     // (27, N)
    float* out = (float*)d_out;                     // (CELLS, 64)

    int* pf = (int*)d_ws;                           // 4.57 MB padded featmap

    (void)hipMemsetAsync(pf, 0, (size_t)PF_INTS * sizeof(int), stream);
    {
        int block = 256;
        int grid = (N_ + block - 1) / block;
        build_featmap_kernel<<<grid, block, 0, stream>>>(scatter, feat, pf);
    }

    // MEASUREMENT: reps=6 so the conv dispatch dominates rocprof top-5.
    {
        dim3 block(256, 1, 1);
        dim3 grid((HW_ / 16) / 4, (B_ * D_) / ZCHUNK, 1);   // 625 x 4
        conv_mfma_kernel<<<grid, block, 0, stream>>>(pf, weight, gamma,
                                                     beta, out, 6);
    }
}

// Round 11
// 266.940 us; speedup vs baseline: 2.4778x; 2.4778x over previous
//
#include <hip/hip_runtime.h>
#include <cstddef>
#include <cstdint>

#define B_ 2
#define D_ 12
#define H_ 200
#define W_ 200
#define HW_ (H_ * W_)
#define CELLS_ (B_ * D_ * H_ * W_)   // 960000
#define N_ 60000
#define CIN_ 2
#define COUT_ 64
#define K27 27
#define EPS_ 1e-5f
#define ZCHUNK 6                      // z-planes per block (12 % 6 == 0)

// padded dense feature map: [B][D+2][H+2][W+2] of packed fp16x2 (4 B/cell)
#define PD (D_ + 2)
#define PH (H_ + 2)
#define PW (W_ + 2)
#define PLANE (PH * PW)               // 40804
#define PF_INTS (B_ * PD * PLANE)     // 1,142,512 ints = 4.57 MB

// LDS store-transpose tile: 16 cells x 64 ch, +4-word row pad (bank spread)
#define LROW 68                       // 64 + 4 pad
#define LTILE (16 * LROW)             // 1088 floats per wave

typedef float  f32x4 __attribute__((ext_vector_type(4)));
typedef __fp16 h16x8 __attribute__((ext_vector_type(8)));
typedef __fp16 h16x2 __attribute__((ext_vector_type(2)));

union h2u   { h16x2 h; int u; };
union fragu { h16x8 v; int i[4]; };

__device__ __forceinline__ int pack_h2(float a, float b) {
    h2u t; t.h = __builtin_amdgcn_cvt_pkrtz(a, b); return t.u;
}

// ---------------------------------------------------------------------------
// Kernel A: build dense zero-padded fp16 feature map from scatter[13].
// ---------------------------------------------------------------------------
__global__ void build_featmap_kernel(const int* __restrict__ scatter,
                                     const float* __restrict__ feat,
                                     int* __restrict__ pf) {
    int n = blockIdx.x * blockDim.x + threadIdx.x;
    if (n >= N_) return;
    int lin = scatter[13 * N_ + n];
    int b = lin / (D_ * HW_);
    int r = lin % (D_ * HW_);
    int z = r / HW_;  r %= HW_;
    int y = r / W_;
    int x = r % W_;
    float2 f = *reinterpret_cast<const float2*>(feat + n * CIN_);
    pf[((b * PD + z + 1) * PH + y + 1) * PW + (x + 1)] = pack_h2(f.x, f.y);
}

// ---------------------------------------------------------------------------
// DPP 16-lane allreduce-add (VALU pipe, no LDS).
// ---------------------------------------------------------------------------
template <int CTRL>
__device__ __forceinline__ float dpp_add(float v) {
    int t = __builtin_amdgcn_update_dpp(
        0, __float_as_int(v), CTRL, 0xF, 0xF, true);
    return v + __int_as_float(t);
}
__device__ __forceinline__ float row16_allreduce_add(float v) {
    v = dpp_add<0x140>(v);  // row_mirror
    v = dpp_add<0x141>(v);  // row_half_mirror
    v = dpp_add<0x4E>(v);   // quad_perm i^2
    v = dpp_add<0xB1>(v);   // quad_perm i^1
    return v;
}

// ---------------------------------------------------------------------------
// Kernel B, round-11: MFMA conv + LDS-BOUNCE STORE TRANSPOSE.
// Round-10 counters showed the epilogue's 16 scalar nt dword stores give
// only 3.4 TB/s (64B partial HBM bursts, nt bypasses L2 merging) — the
// hidden 2x tax on every kernel this session. Fix: LN results bounce
// through a per-wave LDS tile (write: 2-way bank alias = free; read:
// m134-linear minimum), then 4x nontemporal dwordx4 stores, each 1KB
// contiguous per wave -> full-line HBM bursts.
// ---------------------------------------------------------------------------
__global__ __launch_bounds__(256) void conv_mfma_kernel(
        const int* __restrict__ pf,
        const float* __restrict__ weight,
        const float* __restrict__ gamma,
        const float* __restrict__ beta,
        float* __restrict__ out) {
    __shared__ float lsb[4][LTILE];     // 17.4 KB: one 4KB+pad tile per wave

    const int tid  = threadIdx.x;
    const int lane = tid & 63;
    const int wid  = tid >> 6;          // wave in block, 0..3
    const int col  = lane & 15;         // cell-in-strip (A row) / channel-low
    const int grp  = lane >> 4;         // k-slice group, 0..3

    const int ps = blockIdx.x * 4 + wid;        // plane strip id, 0..2499
    const int f  = ps * 16 + col;               // in-plane flat cell
    const int y  = f / W_;
    const int x  = f % W_;

    const int bz0 = blockIdx.y * ZCHUNK;        // first bz of chunk
    const int b   = (bz0 >= D_) ? 1 : 0;        // chunk never straddles b
    const int z0  = bz0 - b * D_;

    // ---- per-lane A voffsets: 2 K-steps x 4 taps (z-invariant) ----
    int voff[2][4];
    #pragma unroll
    for (int s = 0; s < 2; ++s) {
        #pragma unroll
        for (int i = 0; i < 4; ++i) {
            int t = grp * 4 + 16 * s + i;
            if (t <= 26) {
                int dz = t / 9, rr = t % 9, dy = rr / 3, dx = rr % 3;
                voff[s][i] = dz * PLANE + (y + dy) * PW + (x + dx);
            } else {
                voff[s][i] = 0;         // pad slot: reads padding zero
            }
        }
    }

    // ---- B fragments: same slot enumeration as A ----
    fragu bfr[2][4];
    #pragma unroll
    for (int s = 0; s < 2; ++s) {
        #pragma unroll
        for (int nt = 0; nt < 4; ++nt) {
            #pragma unroll
            for (int j2 = 0; j2 < 4; ++j2) {
                int t = grp * 4 + 16 * s + j2;
                float w0 = 0.f, w1 = 0.f;
                if (t <= 26) {
                    w0 = weight[t * (CIN_ * COUT_) + nt * 16 + col];
                    w1 = weight[t * (CIN_ * COUT_) + COUT_ + nt * 16 + col];
                }
                bfr[s][nt].i[j2] = pack_h2(w0, w1);
            }
        }
    }

    float gmv[4], btv[4];
    #pragma unroll
    for (int nt = 0; nt < 4; ++nt) {
        gmv[nt] = gamma[nt * 16 + col];
        btv[nt] = beta[nt * 16 + col];
    }

    // LDS bases (immediate-offset friendly: one vaddr each, imm offsets)
    float*       lw = &lsb[wid][grp * (4 * LROW) + col];        // write base
    const float* lr = &lsb[wid][grp * LROW + col * 4];          // read base
    // global store base: wave tile start + lane*4 floats
    const size_t gsb = (size_t)ps * (16 * COUT_) + lane * 4;

    for (int j = 0; j < ZCHUNK; ++j) {
        const int z  = z0 + j;
        const int bz = bz0 + j;
        const int zb = (b * PD + z) * PLANE;

        fragu af0, af1;
        #pragma unroll
        for (int i = 0; i < 4; ++i) af0.i[i] = pf[zb + voff[0][i]];
        #pragma unroll
        for (int i = 0; i < 4; ++i) af1.i[i] = pf[zb + voff[1][i]];

        int nz = 0;
        #pragma unroll
        for (int i = 0; i < 4; ++i) nz |= af0.i[i] & 0x7FFF7FFF;
        #pragma unroll
        for (int i = 0; i < 4; ++i) nz |= af1.i[i] & 0x7FFF7FFF;
        unsigned long long bal = __ballot(nz != 0);
        unsigned wfold = (unsigned)bal | (unsigned)(bal >> 16)
                       | (unsigned)(bal >> 32) | (unsigned)(bal >> 48);
        unsigned act4 = (wfold >> (grp * 4)) & 0xF;

        f32x4 acc[4];
        #pragma unroll
        for (int nt = 0; nt < 4; ++nt) {
            acc[nt] = (f32x4){0.f, 0.f, 0.f, 0.f};
            acc[nt] = __builtin_amdgcn_mfma_f32_16x16x32_f16(
                          af0.v, bfr[0][nt].v, acc[nt], 0, 0, 0);
            acc[nt] = __builtin_amdgcn_mfma_f32_16x16x32_f16(
                          af1.v, bfr[1][nt].v, acc[nt], 0, 0, 0);
        }

        // ---- LN + ReLU -> LDS tile (cell-major rows, +4 pad) ----
        #pragma unroll
        for (int jj = 0; jj < 4; ++jj) {
            float a0 = acc[0][jj], a1 = acc[1][jj],
                  a2 = acc[2][jj], a3 = acc[3][jj];
            float s  = a0 + a1 + a2 + a3;
            float s2 = a0 * a0 + a1 * a1 + a2 * a2 + a3 * a3;
            s  = row16_allreduce_add(s);
            s2 = row16_allreduce_add(s2);
            float mu  = s * (1.0f / COUT_);
            float var = s2 * (1.0f / COUT_) - mu * mu;
            float inv = rsqrtf(var + EPS_);
            bool actj = (act4 >> jj) & 1;
            #pragma unroll
            for (int nt = 0; nt < 4; ++nt) {
                float v  = acc[nt][jj];
                float rv = fmaxf((v - mu) * inv * gmv[nt] + btv[nt], 0.0f);
                rv = actj ? rv : 0.0f;
                lw[jj * LROW + nt * 16] = rv;       // ds_write, imm offset
            }
        }

        // same-wave LDS handoff: drain ds_writes, block reordering
        asm volatile("s_waitcnt lgkmcnt(0)" ::: "memory");

        // ---- read back transposed + 4x contiguous 1KB nt stores ----
        float* op = out + (size_t)bz * (HW_ * COUT_) + gsb;
        #pragma unroll
        for (int it = 0; it < 4; ++it) {
            f32x4 v = *reinterpret_cast<const f32x4*>(lr + it * (4 * LROW));
            __builtin_nontemporal_store(
                v, reinterpret_cast<f32x4*>(op + it * 256));
        }
    }
}

extern "C" void kernel_launch(void* const* d_in, const int* in_sizes, int n_in,
                              void* d_out, int out_size, void* d_ws, size_t ws_size,
                              hipStream_t stream) {
    const float* feat    = (const float*)d_in[0];   // (N, 2)
    const float* weight  = (const float*)d_in[1];   // (27, 2, 64)
    const float* gamma   = (const float*)d_in[2];   // (64,)
    const float* beta    = (const float*)d_in[3];   // (64,)
    const int*   scatter = (const int*)d_in[4];     // (27, N)
    float* out = (float*)d_out;                     // (CELLS, 64)

    int* pf = (int*)d_ws;                           // 4.57 MB padded featmap

    (void)hipMemsetAsync(pf, 0, (size_t)PF_INTS * sizeof(int), stream);
    {
        int block = 256;
        int grid = (N_ + block - 1) / block;
        build_featmap_kernel<<<grid, block, 0, stream>>>(scatter, feat, pf);
    }

    // dense MFMA conv + LN + ReLU + LDS store-transpose
    {
        dim3 block(256, 1, 1);
        dim3 grid((HW_ / 16) / 4, (B_ * D_) / ZCHUNK, 1);   // 625 x 4
        conv_mfma_kernel<<<grid, block, 0, stream>>>(pf, weight, gamma,
                                                     beta, out);
    }
}